// Round 2
// baseline (582.004 us; speedup 1.0000x reference)
//
#include <hip/hip_runtime.h>
#include <math.h>

#define N 4096
#define D 512
#define KPOS 5
#define KNEG 10

// ---------------------------------------------------------------------------
// Kernel 1: row-wise L2 normalize anchor (eps 1e-8) and sample (eps 1e-12).
// One wave per row; 4 waves per block. rows 0..4095 = anchor, 4096..8191 = sample.
// ---------------------------------------------------------------------------
__global__ __launch_bounds__(256) void norm_kernel(const float* __restrict__ anchor,
                                                   const float* __restrict__ sample,
                                                   float* __restrict__ a_norm,
                                                   float* __restrict__ s_norm) {
    const int wave = threadIdx.x >> 6, lane = threadIdx.x & 63;
    const int row = blockIdx.x * 4 + wave;
    const float* in;
    float* out;
    float eps;
    if (row < N) {
        in = anchor + (size_t)row * D;
        out = a_norm + (size_t)row * D;
        eps = 1e-8f;
    } else {
        in = sample + (size_t)(row - N) * D;
        out = s_norm + (size_t)(row - N) * D;
        eps = 1e-12f;
    }
    float v[8];
    float ss = 0.f;
#pragma unroll
    for (int e = 0; e < 8; ++e) {
        v[e] = in[lane + 64 * e];
        ss = fmaf(v[e], v[e], ss);
    }
#pragma unroll
    for (int off = 32; off > 0; off >>= 1) ss += __shfl_xor(ss, off);
    const float denom = fmaxf(sqrtf(ss), eps);
#pragma unroll
    for (int e = 0; e < 8; ++e) out[lane + 64 * e] = v[e] / denom;
}

// ---------------------------------------------------------------------------
// Kernel 2: sim = An @ An^T, fp32 VALU GEMM.
// 128x128 block tile, BK=16, 256 threads, 8x8 per thread.
// LDS stored K-major (transposed) so fragment reads are float4 (ds_read_b128).
// ---------------------------------------------------------------------------
__global__ __launch_bounds__(256) void gemm_aat(const float* __restrict__ An,
                                                float* __restrict__ C) {
    __shared__ __align__(16) float As[16][132];
    __shared__ __align__(16) float Bs[16][132];
    const int bi = blockIdx.y, bj = blockIdx.x;
    const int t = threadIdx.x;
    const int tx = t & 15, ty = t >> 4;
    const int rowA = bi * 128, rowB = bj * 128;

    float acc[8][8];
#pragma unroll
    for (int r = 0; r < 8; ++r)
#pragma unroll
        for (int c = 0; c < 8; ++c) acc[r][c] = 0.f;

    for (int kc = 0; kc < D; kc += 16) {
#pragma unroll
        for (int i = 0; i < 2; ++i) {
            const int e = t + i * 256;       // float4 index within the 128x16 tile
            const int r = e >> 2;            // row 0..127
            const int kq = (e & 3) << 2;     // k offset 0,4,8,12
            const float4 av = *(const float4*)(An + (size_t)(rowA + r) * D + kc + kq);
            const float4 bv = *(const float4*)(An + (size_t)(rowB + r) * D + kc + kq);
            As[kq + 0][r] = av.x; As[kq + 1][r] = av.y; As[kq + 2][r] = av.z; As[kq + 3][r] = av.w;
            Bs[kq + 0][r] = bv.x; Bs[kq + 1][r] = bv.y; Bs[kq + 2][r] = bv.z; Bs[kq + 3][r] = bv.w;
        }
        __syncthreads();
#pragma unroll
        for (int k = 0; k < 16; ++k) {
            float a[8], b[8];
            *(float4*)&a[0] = *(const float4*)&As[k][ty * 8];
            *(float4*)&a[4] = *(const float4*)&As[k][ty * 8 + 4];
            *(float4*)&b[0] = *(const float4*)&Bs[k][tx * 8];
            *(float4*)&b[4] = *(const float4*)&Bs[k][tx * 8 + 4];
#pragma unroll
            for (int r = 0; r < 8; ++r)
#pragma unroll
                for (int c = 0; c < 8; ++c) acc[r][c] = fmaf(a[r], b[c], acc[r][c]);
        }
        __syncthreads();
    }

#pragma unroll
    for (int r = 0; r < 8; ++r) {
        const size_t row = (size_t)(rowA + ty * 8 + r) * N + rowB + tx * 8;
        *(float4*)(C + row) = make_float4(acc[r][0], acc[r][1], acc[r][2], acc[r][3]);
        *(float4*)(C + row + 4) = make_float4(acc[r][4], acc[r][5], acc[r][6], acc[r][7]);
    }
}

// ---------------------------------------------------------------------------
// Kernel 3: per-row top-5 (max, descending, stable) and bottom-10 (min).
// One block (256 threads) per row; iterative block-wide arg-extremum with
// lower-index tie-break == jax.lax.top_k stable order.
// ---------------------------------------------------------------------------
__global__ __launch_bounds__(256) void topk_kernel(const float* __restrict__ sim,
                                                   int* __restrict__ pos_idx,
                                                   int* __restrict__ neg_idx) {
    __shared__ float sval[256];
    __shared__ int sidx[256];
    const int row = blockIdx.x;
    const int t = threadIdx.x;
    const float* s = sim + (size_t)row * N;
    float v[16];
#pragma unroll
    for (int e = 0; e < 16; ++e) v[e] = s[t + 256 * e];

    // ---- top-5 largest ----
    unsigned excl = 0;
    for (int it = 0; it < KPOS; ++it) {
        float bv = -__builtin_inff();
        int bidx = N;
#pragma unroll
        for (int e = 0; e < 16; ++e) {
            if (excl & (1u << e)) continue;
            const float val = v[e];
            const int idx = t + 256 * e;
            if (val > bv || (val == bv && idx < bidx)) { bv = val; bidx = idx; }
        }
        sval[t] = bv; sidx[t] = bidx;
        __syncthreads();
        for (int st = 128; st > 0; st >>= 1) {
            if (t < st) {
                const float ov = sval[t + st];
                const int oi = sidx[t + st];
                if (ov > sval[t] || (ov == sval[t] && oi < sidx[t])) { sval[t] = ov; sidx[t] = oi; }
            }
            __syncthreads();
        }
        const int widx = sidx[0];
        if (t == 0) pos_idx[row * KPOS + it] = widx;
        if ((widx & 255) == t) excl |= 1u << (widx >> 8);
        __syncthreads();
    }

    // ---- bottom-10 smallest ----
    excl = 0;
    for (int it = 0; it < KNEG; ++it) {
        float bv = __builtin_inff();
        int bidx = N;
#pragma unroll
        for (int e = 0; e < 16; ++e) {
            if (excl & (1u << e)) continue;
            const float val = v[e];
            const int idx = t + 256 * e;
            if (val < bv || (val == bv && idx < bidx)) { bv = val; bidx = idx; }
        }
        sval[t] = bv; sidx[t] = bidx;
        __syncthreads();
        for (int st = 128; st > 0; st >>= 1) {
            if (t < st) {
                const float ov = sval[t + st];
                const int oi = sidx[t + st];
                if (ov < sval[t] || (ov == sval[t] && oi < sidx[t])) { sval[t] = ov; sidx[t] = oi; }
            }
            __syncthreads();
        }
        const int widx = sidx[0];
        if (t == 0) neg_idx[row * KNEG + it] = widx;
        if ((widx & 255) == t) excl |= 1u << (widx >> 8);
        __syncthreads();
    }
}

// ---------------------------------------------------------------------------
// Kernel 4: InfoNCE loss. One wave per output row j in [0, 5N).
//   i_q = j mod N (query = tile(sample,(5,1)))
//   i_a = j / 5   (pos/neg indexed anchor-major)
//   logits = {q.pos, q.neg_k} / T ; loss_j = lse - l0 ; out = mean_j loss_j
// Each block covers 4 rows (4 waves of 64 lanes).
// ---------------------------------------------------------------------------
__global__ __launch_bounds__(256) void loss_kernel(const float* __restrict__ s_norm,
                                                   const int* __restrict__ pos_idx,
                                                   const int* __restrict__ neg_idx,
                                                   float* __restrict__ out) {
    const int wave = threadIdx.x >> 6, lane = threadIdx.x & 63;
    const int j = blockIdx.x * 4 + wave;
    const int ia = j / 5;
    const int p = j - ia * 5;
    const int iq = j & (N - 1);

    const float* q = s_norm + (size_t)iq * D;
    float qv[8];
#pragma unroll
    for (int e = 0; e < 8; ++e) qv[e] = q[lane + 64 * e];

    const int pi = pos_idx[ia * KPOS + p];
    const float* pv = s_norm + (size_t)pi * D;
    float accp = 0.f;
#pragma unroll
    for (int e = 0; e < 8; ++e) accp = fmaf(qv[e], pv[lane + 64 * e], accp);

    float accn[KNEG];
#pragma unroll
    for (int k = 0; k < KNEG; ++k) {
        const float* nv = s_norm + (size_t)neg_idx[ia * KNEG + k] * D;
        float a = 0.f;
#pragma unroll
        for (int e = 0; e < 8; ++e) a = fmaf(qv[e], nv[lane + 64 * e], a);
        accn[k] = a;
    }

#pragma unroll
    for (int off = 32; off > 0; off >>= 1) {
        accp += __shfl_xor(accp, off);
#pragma unroll
        for (int k = 0; k < KNEG; ++k) accn[k] += __shfl_xor(accn[k], off);
    }

    if (lane == 0) {
        const float l0 = accp * 10.f;  // /T, T=0.1
        float m = l0;
        float ln[KNEG];
#pragma unroll
        for (int k = 0; k < KNEG; ++k) {
            ln[k] = accn[k] * 10.f;
            m = fmaxf(m, ln[k]);
        }
        float ssum = expf(l0 - m);
#pragma unroll
        for (int k = 0; k < KNEG; ++k) ssum += expf(ln[k] - m);
        const float term = logf(ssum) + m - l0;  // = lse - l0 = -log_softmax[0]
        atomicAdd(out, term * (1.0f / (float)(N * KPOS)));
    }
}

// ---------------------------------------------------------------------------
extern "C" void kernel_launch(void* const* d_in, const int* in_sizes, int n_in,
                              void* d_out, int out_size, void* d_ws, size_t ws_size,
                              hipStream_t stream) {
    const float* anchor = (const float*)d_in[0];
    const float* sample = (const float*)d_in[1];
    float* out = (float*)d_out;

    char* ws = (char*)d_ws;
    float* a_norm = (float*)ws;                                   //  8 MiB
    float* s_norm = (float*)(ws + (size_t)8 * 1024 * 1024);       //  8 MiB
    float* sim    = (float*)(ws + (size_t)16 * 1024 * 1024);      // 64 MiB
    int* pos_idx  = (int*)(ws + (size_t)80 * 1024 * 1024);        // 80 KiB
    int* neg_idx  = (int*)(ws + (size_t)80 * 1024 * 1024 + (size_t)N * KPOS * sizeof(int));

    norm_kernel<<<2048, 256, 0, stream>>>(anchor, sample, a_norm, s_norm);

    dim3 ggrid(N / 128, N / 128);
    gemm_aat<<<ggrid, 256, 0, stream>>>(a_norm, sim);

    topk_kernel<<<N, 256, 0, stream>>>(sim, pos_idx, neg_idx);

    hipMemsetAsync(d_out, 0, sizeof(float), stream);
    // 4 rows (waves) per block -> 5N/4 blocks.
    loss_kernel<<<(N * KPOS) / 4, 256, 0, stream>>>(s_norm, pos_idx, neg_idx, out);
}

// Round 3
// 357.251 us; speedup vs baseline: 1.6291x; 1.6291x over previous
//
#include <hip/hip_runtime.h>
#include <math.h>

#define N 4096
#define D 512
#define KPOS 5
#define KNEG 10

// ---------------------------------------------------------------------------
// Kernel 1: row-wise L2 normalize anchor (eps 1e-8) and sample (eps 1e-12).
// One wave per row; 4 waves per block. rows 0..4095 = anchor, 4096..8191 = sample.
// ---------------------------------------------------------------------------
__global__ __launch_bounds__(256) void norm_kernel(const float* __restrict__ anchor,
                                                   const float* __restrict__ sample,
                                                   float* __restrict__ a_norm,
                                                   float* __restrict__ s_norm) {
    const int wave = threadIdx.x >> 6, lane = threadIdx.x & 63;
    const int row = blockIdx.x * 4 + wave;
    const float* in;
    float* out;
    float eps;
    if (row < N) {
        in = anchor + (size_t)row * D;
        out = a_norm + (size_t)row * D;
        eps = 1e-8f;
    } else {
        in = sample + (size_t)(row - N) * D;
        out = s_norm + (size_t)(row - N) * D;
        eps = 1e-12f;
    }
    float v[8];
    float ss = 0.f;
#pragma unroll
    for (int e = 0; e < 8; ++e) {
        v[e] = in[lane + 64 * e];
        ss = fmaf(v[e], v[e], ss);
    }
#pragma unroll
    for (int off = 32; off > 0; off >>= 1) ss += __shfl_xor(ss, off);
    const float denom = fmaxf(sqrtf(ss), eps);
#pragma unroll
    for (int e = 0; e < 8; ++e) out[lane + 64 * e] = v[e] / denom;
}

// ---------------------------------------------------------------------------
// Kernel 2: sim = An @ An^T, fp32 VALU GEMM.
// 128x128 block tile, BK=16, 256 threads, 8x8 per thread.
// LDS stored K-major (transposed) so fragment reads are float4 (ds_read_b128).
// ---------------------------------------------------------------------------
__global__ __launch_bounds__(256) void gemm_aat(const float* __restrict__ An,
                                                float* __restrict__ C) {
    __shared__ __align__(16) float As[16][132];
    __shared__ __align__(16) float Bs[16][132];
    const int bi = blockIdx.y, bj = blockIdx.x;
    const int t = threadIdx.x;
    const int tx = t & 15, ty = t >> 4;
    const int rowA = bi * 128, rowB = bj * 128;

    float acc[8][8];
#pragma unroll
    for (int r = 0; r < 8; ++r)
#pragma unroll
        for (int c = 0; c < 8; ++c) acc[r][c] = 0.f;

    for (int kc = 0; kc < D; kc += 16) {
#pragma unroll
        for (int i = 0; i < 2; ++i) {
            const int e = t + i * 256;       // float4 index within the 128x16 tile
            const int r = e >> 2;            // row 0..127
            const int kq = (e & 3) << 2;     // k offset 0,4,8,12
            const float4 av = *(const float4*)(An + (size_t)(rowA + r) * D + kc + kq);
            const float4 bv = *(const float4*)(An + (size_t)(rowB + r) * D + kc + kq);
            As[kq + 0][r] = av.x; As[kq + 1][r] = av.y; As[kq + 2][r] = av.z; As[kq + 3][r] = av.w;
            Bs[kq + 0][r] = bv.x; Bs[kq + 1][r] = bv.y; Bs[kq + 2][r] = bv.z; Bs[kq + 3][r] = bv.w;
        }
        __syncthreads();
#pragma unroll
        for (int k = 0; k < 16; ++k) {
            float a[8], b[8];
            *(float4*)&a[0] = *(const float4*)&As[k][ty * 8];
            *(float4*)&a[4] = *(const float4*)&As[k][ty * 8 + 4];
            *(float4*)&b[0] = *(const float4*)&Bs[k][tx * 8];
            *(float4*)&b[4] = *(const float4*)&Bs[k][tx * 8 + 4];
#pragma unroll
            for (int r = 0; r < 8; ++r)
#pragma unroll
                for (int c = 0; c < 8; ++c) acc[r][c] = fmaf(a[r], b[c], acc[r][c]);
        }
        __syncthreads();
    }

#pragma unroll
    for (int r = 0; r < 8; ++r) {
        const size_t row = (size_t)(rowA + ty * 8 + r) * N + rowB + tx * 8;
        *(float4*)(C + row) = make_float4(acc[r][0], acc[r][1], acc[r][2], acc[r][3]);
        *(float4*)(C + row + 4) = make_float4(acc[r][4], acc[r][5], acc[r][6], acc[r][7]);
    }
}

// ---------------------------------------------------------------------------
// Kernel 3: per-row top-5 (max, descending, stable) and bottom-10 (min).
// One block (256 threads) per row; iterative block-wide arg-extremum with
// lower-index tie-break == jax.lax.top_k stable order.
// ---------------------------------------------------------------------------
__global__ __launch_bounds__(256) void topk_kernel(const float* __restrict__ sim,
                                                   int* __restrict__ pos_idx,
                                                   int* __restrict__ neg_idx) {
    __shared__ float sval[256];
    __shared__ int sidx[256];
    const int row = blockIdx.x;
    const int t = threadIdx.x;
    const float* s = sim + (size_t)row * N;
    float v[16];
#pragma unroll
    for (int e = 0; e < 16; ++e) v[e] = s[t + 256 * e];

    // ---- top-5 largest ----
    unsigned excl = 0;
    for (int it = 0; it < KPOS; ++it) {
        float bv = -__builtin_inff();
        int bidx = N;
#pragma unroll
        for (int e = 0; e < 16; ++e) {
            if (excl & (1u << e)) continue;
            const float val = v[e];
            const int idx = t + 256 * e;
            if (val > bv || (val == bv && idx < bidx)) { bv = val; bidx = idx; }
        }
        sval[t] = bv; sidx[t] = bidx;
        __syncthreads();
        for (int st = 128; st > 0; st >>= 1) {
            if (t < st) {
                const float ov = sval[t + st];
                const int oi = sidx[t + st];
                if (ov > sval[t] || (ov == sval[t] && oi < sidx[t])) { sval[t] = ov; sidx[t] = oi; }
            }
            __syncthreads();
        }
        const int widx = sidx[0];
        if (t == 0) pos_idx[row * KPOS + it] = widx;
        if ((widx & 255) == t) excl |= 1u << (widx >> 8);
        __syncthreads();
    }

    // ---- bottom-10 smallest ----
    excl = 0;
    for (int it = 0; it < KNEG; ++it) {
        float bv = __builtin_inff();
        int bidx = N;
#pragma unroll
        for (int e = 0; e < 16; ++e) {
            if (excl & (1u << e)) continue;
            const float val = v[e];
            const int idx = t + 256 * e;
            if (val < bv || (val == bv && idx < bidx)) { bv = val; bidx = idx; }
        }
        sval[t] = bv; sidx[t] = bidx;
        __syncthreads();
        for (int st = 128; st > 0; st >>= 1) {
            if (t < st) {
                const float ov = sval[t + st];
                const int oi = sidx[t + st];
                if (ov < sval[t] || (ov == sval[t] && oi < sidx[t])) { sval[t] = ov; sidx[t] = oi; }
            }
            __syncthreads();
        }
        const int widx = sidx[0];
        if (t == 0) neg_idx[row * KNEG + it] = widx;
        if ((widx & 255) == t) excl |= 1u << (widx >> 8);
        __syncthreads();
    }
}

// ---------------------------------------------------------------------------
// Kernel 4: InfoNCE loss, atomic-light version.
// 320 blocks x 4 waves; each wave processes 16 rows (320*4*16 = 20480 = 5N).
// Per-wave private accumulator -> LDS block reduce -> ONE atomicAdd per block.
// Row mapping: j -> iq = j mod N (query), ia = j/5, p = j%5.
// ---------------------------------------------------------------------------
#define LOSS_BLOCKS 320
#define ROWS_PER_WAVE 16

__global__ __launch_bounds__(256) void loss_kernel(const float* __restrict__ s_norm,
                                                   const int* __restrict__ pos_idx,
                                                   const int* __restrict__ neg_idx,
                                                   float* __restrict__ out) {
    __shared__ float wsum[4];
    const int wave = threadIdx.x >> 6, lane = threadIdx.x & 63;
    const int gwave = blockIdx.x * 4 + wave;   // 0..1279

    float lsum = 0.f;
    for (int rr = 0; rr < ROWS_PER_WAVE; ++rr) {
        const int j = gwave * ROWS_PER_WAVE + rr;
        const int ia = j / 5;
        const int p = j - ia * 5;
        const int iq = j & (N - 1);

        const float* q = s_norm + (size_t)iq * D;
        float qv[8];
#pragma unroll
        for (int e = 0; e < 8; ++e) qv[e] = q[lane + 64 * e];

        const int pi = pos_idx[ia * KPOS + p];
        const float* pv = s_norm + (size_t)pi * D;
        float accp = 0.f;
#pragma unroll
        for (int e = 0; e < 8; ++e) accp = fmaf(qv[e], pv[lane + 64 * e], accp);

        float accn[KNEG];
#pragma unroll
        for (int k = 0; k < KNEG; ++k) {
            const float* nv = s_norm + (size_t)neg_idx[ia * KNEG + k] * D;
            float a = 0.f;
#pragma unroll
            for (int e = 0; e < 8; ++e) a = fmaf(qv[e], nv[lane + 64 * e], a);
            accn[k] = a;
        }

#pragma unroll
        for (int off = 32; off > 0; off >>= 1) {
            accp += __shfl_xor(accp, off);
#pragma unroll
            for (int k = 0; k < KNEG; ++k) accn[k] += __shfl_xor(accn[k], off);
        }

        // lse - l0, computed redundantly on all lanes (uniform) — cheap.
        const float l0 = accp * 10.f;
        float m = l0;
#pragma unroll
        for (int k = 0; k < KNEG; ++k) m = fmaxf(m, accn[k] * 10.f);
        float ssum = expf(l0 - m);
#pragma unroll
        for (int k = 0; k < KNEG; ++k) ssum += expf(accn[k] * 10.f - m);
        lsum += logf(ssum) + m - l0;
    }

    if (lane == 0) wsum[wave] = lsum;
    __syncthreads();
    if (threadIdx.x == 0) {
        const float total = wsum[0] + wsum[1] + wsum[2] + wsum[3];
        atomicAdd(out, total * (1.0f / (float)(N * KPOS)));
    }
}

// ---------------------------------------------------------------------------
extern "C" void kernel_launch(void* const* d_in, const int* in_sizes, int n_in,
                              void* d_out, int out_size, void* d_ws, size_t ws_size,
                              hipStream_t stream) {
    const float* anchor = (const float*)d_in[0];
    const float* sample = (const float*)d_in[1];
    float* out = (float*)d_out;

    char* ws = (char*)d_ws;
    float* a_norm = (float*)ws;                                   //  8 MiB
    float* s_norm = (float*)(ws + (size_t)8 * 1024 * 1024);       //  8 MiB
    float* sim    = (float*)(ws + (size_t)16 * 1024 * 1024);      // 64 MiB
    int* pos_idx  = (int*)(ws + (size_t)80 * 1024 * 1024);        // 80 KiB
    int* neg_idx  = (int*)(ws + (size_t)80 * 1024 * 1024 + (size_t)N * KPOS * sizeof(int));

    norm_kernel<<<2048, 256, 0, stream>>>(anchor, sample, a_norm, s_norm);

    dim3 ggrid(N / 128, N / 128);
    gemm_aat<<<ggrid, 256, 0, stream>>>(a_norm, sim);

    topk_kernel<<<N, 256, 0, stream>>>(sim, pos_idx, neg_idx);

    hipMemsetAsync(d_out, 0, sizeof(float), stream);
    loss_kernel<<<LOSS_BLOCKS, 256, 0, stream>>>(s_norm, pos_idx, neg_idx, out);
}

// Round 4
// 218.256 us; speedup vs baseline: 2.6666x; 1.6368x over previous
//
#include <hip/hip_runtime.h>
#include <math.h>

#define N 4096
#define D 512
#define KPOS 5
#define KNEG 10

typedef short s16x8 __attribute__((ext_vector_type(8)));
typedef float f32x4 __attribute__((ext_vector_type(4)));

__device__ __forceinline__ unsigned short f2bf(float x) {
    unsigned u = __float_as_uint(x);
    unsigned r = (u + 0x7FFFu + ((u >> 16) & 1u)) >> 16;   // RNE
    return (unsigned short)r;
}
__device__ __forceinline__ float bf2f(unsigned short b) {
    return __uint_as_float(((unsigned)b) << 16);
}

// ---------------------------------------------------------------------------
// Kernel 1: normalize. anchor rows (eps 1e-8) -> bf16 hi/lo split (Ahi, Alo).
// sample rows (eps 1e-12) -> fp32 s_norm (for the loss kernel).
// One wave per row, 4 waves/block, 2048 blocks for 8192 rows.
// ---------------------------------------------------------------------------
__global__ __launch_bounds__(256) void norm_kernel(const float* __restrict__ anchor,
                                                   const float* __restrict__ sample,
                                                   unsigned short* __restrict__ Ahi,
                                                   unsigned short* __restrict__ Alo,
                                                   float* __restrict__ s_norm) {
    const int wave = threadIdx.x >> 6, lane = threadIdx.x & 63;
    const int row = blockIdx.x * 4 + wave;
    const bool is_anchor = row < N;
    const float* in = is_anchor ? anchor + (size_t)row * D
                                : sample + (size_t)(row - N) * D;
    const float eps = is_anchor ? 1e-8f : 1e-12f;

    float v[8];
    float ss = 0.f;
#pragma unroll
    for (int e = 0; e < 8; ++e) {
        v[e] = in[lane + 64 * e];
        ss = fmaf(v[e], v[e], ss);
    }
#pragma unroll
    for (int off = 32; off > 0; off >>= 1) ss += __shfl_xor(ss, off);
    const float denom = fmaxf(sqrtf(ss), eps);

    if (is_anchor) {
        unsigned short* hi = Ahi + (size_t)row * D;
        unsigned short* lo = Alo + (size_t)row * D;
#pragma unroll
        for (int e = 0; e < 8; ++e) {
            const float x = v[e] / denom;
            const unsigned short h = f2bf(x);
            hi[lane + 64 * e] = h;
            lo[lane + 64 * e] = f2bf(x - bf2f(h));
        }
    } else {
        float* out = s_norm + (size_t)(row - N) * D;
#pragma unroll
        for (int e = 0; e < 8; ++e) out[lane + 64 * e] = v[e] / denom;
    }
}

// ---------------------------------------------------------------------------
// Kernel 2: sim = (hi+lo)@(hi+lo)^T approx = hi@hi^T + hi@lo^T + lo@hi^T.
// Single bf16 MFMA GEMM with effective K = 3*512 = 1536, phase-selected
// operand pointers. m97 structure: 128x128 tile, BK=64, 4 waves, 16x16x32
// MFMA, global_load_lds width 16, single-buffered LDS.
// ---------------------------------------------------------------------------
__global__ __launch_bounds__(256) void gemm_bf16(const unsigned short* __restrict__ Ahi,
                                                 const unsigned short* __restrict__ Alo,
                                                 float* __restrict__ C) {
    __shared__ __align__(16) unsigned short As[128 * 64];   // 16 KiB
    __shared__ __align__(16) unsigned short Bs[128 * 64];   // 16 KiB

    const int t = threadIdx.x;
    const int l = t & 63;
    const int w = t >> 6;
    const int wr = w >> 1, wc = w & 1;            // wave tile (wr*64, wc*64)
    const int rowA = blockIdx.y * 128;
    const int rowB = blockIdx.x * 128;

    f32x4 acc[4][4];
#pragma unroll
    for (int m = 0; m < 4; ++m)
#pragma unroll
        for (int n = 0; n < 4; ++n) acc[m][n] = (f32x4){0.f, 0.f, 0.f, 0.f};

    const int lrow = l & 15, lgrp = l >> 4;

    for (int kc = 0; kc < 24; ++kc) {
        const int phase = kc >> 3;                // 0: hi*hi, 1: hi*lo, 2: lo*hi
        const int kl = (kc & 7) * 64;             // k offset within 512
        const unsigned short* srcA = (phase == 2) ? Alo : Ahi;
        const unsigned short* srcB = (phase == 1) ? Alo : Ahi;

#pragma unroll
        for (int i = 0; i < 4; ++i) {
            const int c = i * 256 + t;            // 16B chunk id, 0..1023
            const int r = c >> 3;                 // tile row 0..127
            const int ke = (c & 7) * 8;           // k element offset
            __builtin_amdgcn_global_load_lds(
                (const __attribute__((address_space(1))) void*)(srcA + (size_t)(rowA + r) * D + kl + ke),
                (__attribute__((address_space(3))) void*)(As + c * 8), 16, 0, 0);
        }
#pragma unroll
        for (int i = 0; i < 4; ++i) {
            const int c = i * 256 + t;
            const int r = c >> 3;
            const int ke = (c & 7) * 8;
            __builtin_amdgcn_global_load_lds(
                (const __attribute__((address_space(1))) void*)(srcB + (size_t)(rowB + r) * D + kl + ke),
                (__attribute__((address_space(3))) void*)(Bs + c * 8), 16, 0, 0);
        }
        asm volatile("s_waitcnt vmcnt(0)");
        __syncthreads();

#pragma unroll
        for (int kk = 0; kk < 2; ++kk) {
            s16x8 af[4], bfr[4];
#pragma unroll
            for (int m = 0; m < 4; ++m)
                af[m] = *(const s16x8*)&As[(wr * 64 + m * 16 + lrow) * 64 + kk * 32 + lgrp * 8];
#pragma unroll
            for (int n = 0; n < 4; ++n)
                bfr[n] = *(const s16x8*)&Bs[(wc * 64 + n * 16 + lrow) * 64 + kk * 32 + lgrp * 8];
#pragma unroll
            for (int m = 0; m < 4; ++m)
#pragma unroll
                for (int n = 0; n < 4; ++n)
                    acc[m][n] = __builtin_amdgcn_mfma_f32_16x16x32_bf16(af[m], bfr[n], acc[m][n], 0, 0, 0);
        }
        __syncthreads();
    }

    // C/D layout: col = lane&15, row = (lane>>4)*4 + j  [m89-verified]
#pragma unroll
    for (int m = 0; m < 4; ++m) {
#pragma unroll
        for (int n = 0; n < 4; ++n) {
            const int col = rowB + wc * 64 + n * 16 + lrow;
            const int row0 = rowA + wr * 64 + m * 16 + lgrp * 4;
#pragma unroll
            for (int j = 0; j < 4; ++j)
                C[(size_t)(row0 + j) * N + col] = acc[m][n][j];
        }
    }
}

// ---------------------------------------------------------------------------
// Kernel 3: wave-per-row top-5 / bottom-10. No barriers.
// Per-lane sorted insertion (float4-coalesced loads), then shuffle-butterfly
// arg-reduce rounds; winner shifts its register list (static indexing only).
// Comparators replicate jax.lax.top_k stable order (ties -> lower index).
// ---------------------------------------------------------------------------
__global__ __launch_bounds__(256) void topk_kernel(const float* __restrict__ sim,
                                                   int* __restrict__ pos_idx,
                                                   int* __restrict__ neg_idx) {
    const int w = threadIdx.x >> 6, l = threadIdx.x & 63;
    const int row = blockIdx.x * 4 + w;
    const float* s = sim + (size_t)row * N;

    float tv0 = -__builtin_inff(), tv1 = tv0, tv2 = tv0, tv3 = tv0, tv4 = tv0;
    int ti0 = N, ti1 = N, ti2 = N, ti3 = N, ti4 = N;
    float bv0 = __builtin_inff(), bv1 = bv0, bv2 = bv0, bv3 = bv0, bv4 = bv0,
          bv5 = bv0, bv6 = bv0, bv7 = bv0, bv8 = bv0, bv9 = bv0;
    int bi0 = N, bi1 = N, bi2 = N, bi3 = N, bi4 = N, bi5 = N, bi6 = N, bi7 = N, bi8 = N, bi9 = N;

#define TOP_BETTER(v, i, v2, i2) ((v) > (v2) || ((v) == (v2) && (i) < (i2)))
#define BOT_BETTER(v, i, v2, i2) ((v) < (v2) || ((v) == (v2) && (i) < (i2)))

#define INS_TOP(val, idx)                                                      \
    if (TOP_BETTER(val, idx, tv4, ti4)) {                                      \
        tv4 = val; ti4 = idx;                                                  \
        if (TOP_BETTER(tv4, ti4, tv3, ti3)) { float tf = tv3; int tj = ti3; tv3 = tv4; ti3 = ti4; tv4 = tf; ti4 = tj; \
        if (TOP_BETTER(tv3, ti3, tv2, ti2)) { tf = tv2; tj = ti2; tv2 = tv3; ti2 = ti3; tv3 = tf; ti3 = tj;           \
        if (TOP_BETTER(tv2, ti2, tv1, ti1)) { tf = tv1; tj = ti1; tv1 = tv2; ti1 = ti2; tv2 = tf; ti2 = tj;           \
        if (TOP_BETTER(tv1, ti1, tv0, ti0)) { tf = tv0; tj = ti0; tv0 = tv1; ti0 = ti1; tv1 = tf; ti1 = tj; }}}}      \
    }

#define INS_BOT(val, idx)                                                      \
    if (BOT_BETTER(val, idx, bv9, bi9)) {                                      \
        bv9 = val; bi9 = idx;                                                  \
        if (BOT_BETTER(bv9, bi9, bv8, bi8)) { float tf = bv8; int tj = bi8; bv8 = bv9; bi8 = bi9; bv9 = tf; bi9 = tj; \
        if (BOT_BETTER(bv8, bi8, bv7, bi7)) { tf = bv7; tj = bi7; bv7 = bv8; bi7 = bi8; bv8 = tf; bi8 = tj;           \
        if (BOT_BETTER(bv7, bi7, bv6, bi6)) { tf = bv6; tj = bi6; bv6 = bv7; bi6 = bi7; bv7 = tf; bi7 = tj;           \
        if (BOT_BETTER(bv6, bi6, bv5, bi5)) { tf = bv5; tj = bi5; bv5 = bv6; bi5 = bi6; bv6 = tf; bi6 = tj;           \
        if (BOT_BETTER(bv5, bi5, bv4, bi4)) { tf = bv4; tj = bi4; bv4 = bv5; bi4 = bi5; bv5 = tf; bi5 = tj;           \
        if (BOT_BETTER(bv4, bi4, bv3, bi3)) { tf = bv3; tj = bi3; bv3 = bv4; bi3 = bi4; bv4 = tf; bi4 = tj;           \
        if (BOT_BETTER(bv3, bi3, bv2, bi2)) { tf = bv2; tj = bi2; bv2 = bv3; bi2 = bi3; bv3 = tf; bi3 = tj;           \
        if (BOT_BETTER(bv2, bi2, bv1, bi1)) { tf = bv1; tj = bi1; bv1 = bv2; bi1 = bi2; bv2 = tf; bi2 = tj;           \
        if (BOT_BETTER(bv1, bi1, bv0, bi0)) { tf = bv0; tj = bi0; bv0 = bv1; bi0 = bi1; bv1 = tf; bi1 = tj; }}}}}}}}} \
    }

    for (int e = 0; e < 16; ++e) {
        const int cb = 4 * (l + 64 * e);
        const float4 v4 = *(const float4*)&s[cb];
        INS_TOP(v4.x, cb);
        INS_TOP(v4.y, cb + 1);
        INS_TOP(v4.z, cb + 2);
        INS_TOP(v4.w, cb + 3);
        INS_BOT(v4.x, cb);
        INS_BOT(v4.y, cb + 1);
        INS_BOT(v4.z, cb + 2);
        INS_BOT(v4.w, cb + 3);
    }

    // ---- merge top-5 across the wave ----
    for (int it = 0; it < KPOS; ++it) {
        const float hv = tv0;
        const int hj = ti0;
        float v = hv;
        int i = hj;
#pragma unroll
        for (int off = 32; off > 0; off >>= 1) {
            const float ov = __shfl_xor(v, off);
            const int oi = __shfl_xor(i, off);
            if (TOP_BETTER(ov, oi, v, i)) { v = ov; i = oi; }
        }
        if (l == 0) pos_idx[row * KPOS + it] = i;
        if (hj == i) {  // this lane supplied the winner: pop its head
            tv0 = tv1; ti0 = ti1; tv1 = tv2; ti1 = ti2; tv2 = tv3; ti2 = ti3;
            tv3 = tv4; ti3 = ti4; tv4 = -__builtin_inff(); ti4 = N;
        }
    }

    // ---- merge bottom-10 across the wave ----
    for (int it = 0; it < KNEG; ++it) {
        const float hv = bv0;
        const int hj = bi0;
        float v = hv;
        int i = hj;
#pragma unroll
        for (int off = 32; off > 0; off >>= 1) {
            const float ov = __shfl_xor(v, off);
            const int oi = __shfl_xor(i, off);
            if (BOT_BETTER(ov, oi, v, i)) { v = ov; i = oi; }
        }
        if (l == 0) neg_idx[row * KNEG + it] = i;
        if (hj == i) {
            bv0 = bv1; bi0 = bi1; bv1 = bv2; bi1 = bi2; bv2 = bv3; bi2 = bi3;
            bv3 = bv4; bi3 = bi4; bv4 = bv5; bi4 = bi5; bv5 = bv6; bi5 = bi6;
            bv6 = bv7; bi6 = bi7; bv7 = bv8; bi7 = bi8; bv8 = bv9; bi8 = bi9;
            bv9 = __builtin_inff(); bi9 = N;
        }
    }
}

// ---------------------------------------------------------------------------
// Kernel 4: InfoNCE loss. 320 blocks x 4 waves x 16 rows; one atomic/block.
// ---------------------------------------------------------------------------
#define LOSS_BLOCKS 320
#define ROWS_PER_WAVE 16

__global__ __launch_bounds__(256) void loss_kernel(const float* __restrict__ s_norm,
                                                   const int* __restrict__ pos_idx,
                                                   const int* __restrict__ neg_idx,
                                                   float* __restrict__ out) {
    __shared__ float wsum[4];
    const int wave = threadIdx.x >> 6, lane = threadIdx.x & 63;
    const int gwave = blockIdx.x * 4 + wave;

    float lsum = 0.f;
    for (int rr = 0; rr < ROWS_PER_WAVE; ++rr) {
        const int j = gwave * ROWS_PER_WAVE + rr;
        const int ia = j / 5;
        const int p = j - ia * 5;
        const int iq = j & (N - 1);

        const float* q = s_norm + (size_t)iq * D;
        float qv[8];
#pragma unroll
        for (int e = 0; e < 8; ++e) qv[e] = q[lane + 64 * e];

        const int pi = pos_idx[ia * KPOS + p];
        const float* pv = s_norm + (size_t)pi * D;
        float accp = 0.f;
#pragma unroll
        for (int e = 0; e < 8; ++e) accp = fmaf(qv[e], pv[lane + 64 * e], accp);

        float accn[KNEG];
#pragma unroll
        for (int k = 0; k < KNEG; ++k) {
            const float* nv = s_norm + (size_t)neg_idx[ia * KNEG + k] * D;
            float a = 0.f;
#pragma unroll
            for (int e = 0; e < 8; ++e) a = fmaf(qv[e], nv[lane + 64 * e], a);
            accn[k] = a;
        }

#pragma unroll
        for (int off = 32; off > 0; off >>= 1) {
            accp += __shfl_xor(accp, off);
#pragma unroll
            for (int k = 0; k < KNEG; ++k) accn[k] += __shfl_xor(accn[k], off);
        }

        const float l0 = accp * 10.f;
        float m = l0;
#pragma unroll
        for (int k = 0; k < KNEG; ++k) m = fmaxf(m, accn[k] * 10.f);
        float ssum = expf(l0 - m);
#pragma unroll
        for (int k = 0; k < KNEG; ++k) ssum += expf(accn[k] * 10.f - m);
        lsum += logf(ssum) + m - l0;
    }

    if (lane == 0) wsum[wave] = lsum;
    __syncthreads();
    if (threadIdx.x == 0) {
        const float total = wsum[0] + wsum[1] + wsum[2] + wsum[3];
        atomicAdd(out, total * (1.0f / (float)(N * KPOS)));
    }
}

// ---------------------------------------------------------------------------
extern "C" void kernel_launch(void* const* d_in, const int* in_sizes, int n_in,
                              void* d_out, int out_size, void* d_ws, size_t ws_size,
                              hipStream_t stream) {
    const float* anchor = (const float*)d_in[0];
    const float* sample = (const float*)d_in[1];
    float* out = (float*)d_out;

    char* ws = (char*)d_ws;
    unsigned short* Ahi = (unsigned short*)ws;                              // 4 MiB
    unsigned short* Alo = (unsigned short*)(ws + (size_t)4 * 1024 * 1024);  // 4 MiB
    float* s_norm = (float*)(ws + (size_t)8 * 1024 * 1024);                 // 8 MiB
    float* sim    = (float*)(ws + (size_t)16 * 1024 * 1024);                // 64 MiB
    int* pos_idx  = (int*)(ws + (size_t)80 * 1024 * 1024);
    int* neg_idx  = (int*)(ws + (size_t)80 * 1024 * 1024 + (size_t)N * KPOS * sizeof(int));

    norm_kernel<<<2048, 256, 0, stream>>>(anchor, sample, Ahi, Alo, s_norm);

    dim3 ggrid(N / 128, N / 128);
    gemm_bf16<<<ggrid, 256, 0, stream>>>(Ahi, Alo, sim);

    topk_kernel<<<N / 4, 256, 0, stream>>>(sim, pos_idx, neg_idx);

    hipMemsetAsync(d_out, 0, sizeof(float), stream);
    loss_kernel<<<LOSS_BLOCKS, 256, 0, stream>>>(s_norm, pos_idx, neg_idx, out);
}

// Round 5
// 142.570 us; speedup vs baseline: 4.0822x; 1.5309x over previous
//
#include <hip/hip_runtime.h>
#include <math.h>

#define N 4096
#define D 512
#define KPOS 5
#define KNEG 10

typedef short s16x8 __attribute__((ext_vector_type(8)));
typedef float f32x4 __attribute__((ext_vector_type(4)));

__device__ __forceinline__ unsigned short f2bf(float x) {
    unsigned u = __float_as_uint(x);
    unsigned r = (u + 0x7FFFu + ((u >> 16) & 1u)) >> 16;   // RNE
    return (unsigned short)r;
}
__device__ __forceinline__ float bf2f(unsigned short b) {
    return __uint_as_float(((unsigned)b) << 16);
}
__device__ __forceinline__ unsigned umax_(unsigned a, unsigned b) { return a > b ? a : b; }
__device__ __forceinline__ unsigned umin_(unsigned a, unsigned b) { return a < b ? a : b; }

// ---------------------------------------------------------------------------
// Kernel 1: normalize. anchor rows (eps 1e-8) -> bf16 hi/lo split (Ahi, Alo).
// sample rows (eps 1e-12) -> fp32 s_norm (for the loss kernel).
// ---------------------------------------------------------------------------
__global__ __launch_bounds__(256) void norm_kernel(const float* __restrict__ anchor,
                                                   const float* __restrict__ sample,
                                                   unsigned short* __restrict__ Ahi,
                                                   unsigned short* __restrict__ Alo,
                                                   float* __restrict__ s_norm) {
    const int wave = threadIdx.x >> 6, lane = threadIdx.x & 63;
    const int row = blockIdx.x * 4 + wave;
    const bool is_anchor = row < N;
    const float* in = is_anchor ? anchor + (size_t)row * D
                                : sample + (size_t)(row - N) * D;
    const float eps = is_anchor ? 1e-8f : 1e-12f;

    float v[8];
    float ss = 0.f;
#pragma unroll
    for (int e = 0; e < 8; ++e) {
        v[e] = in[lane + 64 * e];
        ss = fmaf(v[e], v[e], ss);
    }
#pragma unroll
    for (int off = 32; off > 0; off >>= 1) ss += __shfl_xor(ss, off);
    const float denom = fmaxf(sqrtf(ss), eps);

    if (is_anchor) {
        unsigned short* hi = Ahi + (size_t)row * D;
        unsigned short* lo = Alo + (size_t)row * D;
#pragma unroll
        for (int e = 0; e < 8; ++e) {
            const float x = v[e] / denom;
            const unsigned short h = f2bf(x);
            hi[lane + 64 * e] = h;
            lo[lane + 64 * e] = f2bf(x - bf2f(h));
        }
    } else {
        float* out = s_norm + (size_t)(row - N) * D;
#pragma unroll
        for (int e = 0; e < 8; ++e) out[lane + 64 * e] = v[e] / denom;
    }
}

// ---------------------------------------------------------------------------
// Kernel 2: sim = hi@hi^T + hi@lo^T + lo@hi^T (bf16 MFMA, eff. K = 1536).
// 128x128 tile, BK=64, 4 waves, 16x16x32 MFMA.
// Double-buffered LDS with prefetch-before-compute (T3-minimum) and T2 XOR
// swizzle (chunk ^= row&7) applied on the global source (rule #21: linear
// global_load_lds dest + inverse-swizzled source + swizzled ds_read).
// ---------------------------------------------------------------------------
#define TILE (128 * 64)

__device__ __forceinline__ void stage_tile(const unsigned short* __restrict__ sA,
                                           const unsigned short* __restrict__ sB,
                                           unsigned short* As, unsigned short* Bs,
                                           int rowA, int rowB, int kl, int t) {
#pragma unroll
    for (int i = 0; i < 4; ++i) {
        const int c = i * 256 + t;                 // 16B chunk id 0..1023
        const int r = c >> 3;                      // tile row 0..127
        const int ke = ((c & 7) ^ (r & 7)) * 8;    // swizzled k-element offset
        __builtin_amdgcn_global_load_lds(
            (const __attribute__((address_space(1))) void*)(sA + (size_t)(rowA + r) * D + kl + ke),
            (__attribute__((address_space(3))) void*)(As + c * 8), 16, 0, 0);
    }
#pragma unroll
    for (int i = 0; i < 4; ++i) {
        const int c = i * 256 + t;
        const int r = c >> 3;
        const int ke = ((c & 7) ^ (r & 7)) * 8;
        __builtin_amdgcn_global_load_lds(
            (const __attribute__((address_space(1))) void*)(sB + (size_t)(rowB + r) * D + kl + ke),
            (__attribute__((address_space(3))) void*)(Bs + c * 8), 16, 0, 0);
    }
}

__global__ __launch_bounds__(256) void gemm_bf16(const unsigned short* __restrict__ Ahi,
                                                 const unsigned short* __restrict__ Alo,
                                                 float* __restrict__ C) {
    __shared__ __align__(16) unsigned short As[2 * TILE];   // 2 x 16 KiB
    __shared__ __align__(16) unsigned short Bs[2 * TILE];

    const int t = threadIdx.x;
    const int l = t & 63;
    const int w = t >> 6;
    const int wr = w >> 1, wc = w & 1;
    const int rowA = blockIdx.y * 128;
    const int rowB = blockIdx.x * 128;
    const int lrow = l & 15, lgrp = l >> 4;

    f32x4 acc[4][4];
#pragma unroll
    for (int m = 0; m < 4; ++m)
#pragma unroll
        for (int n = 0; n < 4; ++n) acc[m][n] = (f32x4){0.f, 0.f, 0.f, 0.f};

    // prologue: stage tile 0 (phase 0 = hi*hi, kl = 0)
    stage_tile(Ahi, Ahi, As, Bs, rowA, rowB, 0, t);
    __syncthreads();

    for (int kc = 0; kc < 24; ++kc) {
        const int cur = kc & 1;
        if (kc < 23) {
            const int kn = kc + 1;
            const int phase = kn >> 3;             // 0: hi*hi, 1: hi*lo, 2: lo*hi
            const int kl = (kn & 7) * 64;
            stage_tile(phase == 2 ? Alo : Ahi, phase == 1 ? Alo : Ahi,
                       As + (cur ^ 1) * TILE, Bs + (cur ^ 1) * TILE,
                       rowA, rowB, kl, t);
        }

        const char* AsB = (const char*)(As + cur * TILE);
        const char* BsB = (const char*)(Bs + cur * TILE);
#pragma unroll
        for (int kk = 0; kk < 2; ++kk) {
            s16x8 af[4], bfr[4];
#pragma unroll
            for (int m = 0; m < 4; ++m) {
                const int row = wr * 64 + m * 16 + lrow;
                af[m] = *(const s16x8*)(AsB + row * 128 + (((kk * 4 + lgrp) ^ (row & 7)) * 16));
            }
#pragma unroll
            for (int n = 0; n < 4; ++n) {
                const int row = wc * 64 + n * 16 + lrow;
                bfr[n] = *(const s16x8*)(BsB + row * 128 + (((kk * 4 + lgrp) ^ (row & 7)) * 16));
            }
#pragma unroll
            for (int m = 0; m < 4; ++m)
#pragma unroll
                for (int n = 0; n < 4; ++n)
                    acc[m][n] = __builtin_amdgcn_mfma_f32_16x16x32_bf16(af[m], bfr[n], acc[m][n], 0, 0, 0);
        }
        // drains this iter's prefetch (vmcnt) AND fences buffer reuse.
        __syncthreads();
    }

    // C/D layout: col = lane&15, row = (lane>>4)*4 + j
#pragma unroll
    for (int m = 0; m < 4; ++m) {
#pragma unroll
        for (int n = 0; n < 4; ++n) {
            const int col = rowB + wc * 64 + n * 16 + lrow;
            const int row0 = rowA + wr * 64 + m * 16 + lgrp * 4;
#pragma unroll
            for (int j = 0; j < 4; ++j)
                C[(size_t)(row0 + j) * N + col] = acc[m][n][j];
        }
    }
}

// ---------------------------------------------------------------------------
// Kernel 3: wave-per-row top-5 / bottom-10, branchless on packed u32 keys.
// key = (monotone_fp32_bits & 0xFFFFF000) | idx12 (idx complemented for top
// so equal truncated values resolve to the LOWER index = jax stable order).
// Insert = max/min bubble cascade (no branches, no divergence); merge =
// wave-wide key max/min reduce + pop.
// ---------------------------------------------------------------------------
__global__ __launch_bounds__(256) void topk_kernel(const float* __restrict__ sim,
                                                   int* __restrict__ pos_idx,
                                                   int* __restrict__ neg_idx) {
    const int w = threadIdx.x >> 6, l = threadIdx.x & 63;
    const int row = blockIdx.x * 4 + w;
    const float* s = sim + (size_t)row * N;

    unsigned tk[KPOS], bk[KNEG];
#pragma unroll
    for (int q = 0; q < KPOS; ++q) tk[q] = 0u;
#pragma unroll
    for (int q = 0; q < KNEG; ++q) bk[q] = 0xFFFFFFFFu;

    for (int e = 0; e < 16; ++e) {
        const int base = 4 * (l + 64 * e);
        const float4 v4 = *(const float4*)&s[base];
        const float vv[4] = {v4.x, v4.y, v4.z, v4.w};
#pragma unroll
        for (int j = 0; j < 4; ++j) {
            unsigned u = __float_as_uint(vv[j]);
            u ^= ((unsigned)((int)u >> 31)) | 0x80000000u;   // monotone map
            const unsigned kv = u & 0xFFFFF000u;
            const int idx = base + j;

            unsigned c = kv | (unsigned)(4095 - idx);        // top key
#pragma unroll
            for (int q = 0; q < KPOS - 1; ++q) {
                const unsigned x = umax_(tk[q], c);
                c = umin_(tk[q], c);
                tk[q] = x;
            }
            tk[KPOS - 1] = umax_(tk[KPOS - 1], c);

            c = kv | (unsigned)idx;                          // bot key
#pragma unroll
            for (int q = 0; q < KNEG - 1; ++q) {
                const unsigned x = umin_(bk[q], c);
                c = umax_(bk[q], c);
                bk[q] = x;
            }
            bk[KNEG - 1] = umax_(bk[KNEG - 1], c);
        }
    }

    // ---- merge top-5 across the wave ----
    for (int it = 0; it < KPOS; ++it) {
        unsigned m = tk[0];
#pragma unroll
        for (int off = 32; off > 0; off >>= 1) m = umax_(m, (unsigned)__shfl_xor((int)m, off));
        if (l == 0) pos_idx[row * KPOS + it] = 4095 - (int)(m & 0xFFFu);
        if (tk[0] == m) {   // unique key -> exactly one lane pops
#pragma unroll
            for (int q = 0; q < KPOS - 1; ++q) tk[q] = tk[q + 1];
            tk[KPOS - 1] = 0u;
        }
    }

    // ---- merge bottom-10 across the wave ----
    for (int it = 0; it < KNEG; ++it) {
        unsigned m = bk[0];
#pragma unroll
        for (int off = 32; off > 0; off >>= 1) m = umin_(m, (unsigned)__shfl_xor((int)m, off));
        if (l == 0) neg_idx[row * KNEG + it] = (int)(m & 0xFFFu);
        if (bk[0] == m) {
#pragma unroll
            for (int q = 0; q < KNEG - 1; ++q) bk[q] = bk[q + 1];
            bk[KNEG - 1] = 0xFFFFFFFFu;
        }
    }
}

// ---------------------------------------------------------------------------
// Kernel 4: InfoNCE loss. 320 blocks x 4 waves x 16 rows; one atomic/block.
// ---------------------------------------------------------------------------
#define LOSS_BLOCKS 320
#define ROWS_PER_WAVE 16

__global__ __launch_bounds__(256) void loss_kernel(const float* __restrict__ s_norm,
                                                   const int* __restrict__ pos_idx,
                                                   const int* __restrict__ neg_idx,
                                                   float* __restrict__ out) {
    __shared__ float wsum[4];
    const int wave = threadIdx.x >> 6, lane = threadIdx.x & 63;
    const int gwave = blockIdx.x * 4 + wave;

    float lsum = 0.f;
    for (int rr = 0; rr < ROWS_PER_WAVE; ++rr) {
        const int j = gwave * ROWS_PER_WAVE + rr;
        const int ia = j / 5;
        const int p = j - ia * 5;
        const int iq = j & (N - 1);

        const float* q = s_norm + (size_t)iq * D;
        float qv[8];
#pragma unroll
        for (int e = 0; e < 8; ++e) qv[e] = q[lane + 64 * e];

        const int pi = pos_idx[ia * KPOS + p];
        const float* pv = s_norm + (size_t)pi * D;
        float accp = 0.f;
#pragma unroll
        for (int e = 0; e < 8; ++e) accp = fmaf(qv[e], pv[lane + 64 * e], accp);

        float accn[KNEG];
#pragma unroll
        for (int k = 0; k < KNEG; ++k) {
            const float* nv = s_norm + (size_t)neg_idx[ia * KNEG + k] * D;
            float a = 0.f;
#pragma unroll
            for (int e = 0; e < 8; ++e) a = fmaf(qv[e], nv[lane + 64 * e], a);
            accn[k] = a;
        }

#pragma unroll
        for (int off = 32; off > 0; off >>= 1) {
            accp += __shfl_xor(accp, off);
#pragma unroll
            for (int k = 0; k < KNEG; ++k) accn[k] += __shfl_xor(accn[k], off);
        }

        const float l0 = accp * 10.f;
        float m = l0;
#pragma unroll
        for (int k = 0; k < KNEG; ++k) m = fmaxf(m, accn[k] * 10.f);
        float ssum = expf(l0 - m);
#pragma unroll
        for (int k = 0; k < KNEG; ++k) ssum += expf(accn[k] * 10.f - m);
        lsum += logf(ssum) + m - l0;
    }

    if (lane == 0) wsum[wave] = lsum;
    __syncthreads();
    if (threadIdx.x == 0) {
        const float total = wsum[0] + wsum[1] + wsum[2] + wsum[3];
        atomicAdd(out, total * (1.0f / (float)(N * KPOS)));
    }
}

// ---------------------------------------------------------------------------
extern "C" void kernel_launch(void* const* d_in, const int* in_sizes, int n_in,
                              void* d_out, int out_size, void* d_ws, size_t ws_size,
                              hipStream_t stream) {
    const float* anchor = (const float*)d_in[0];
    const float* sample = (const float*)d_in[1];
    float* out = (float*)d_out;

    char* ws = (char*)d_ws;
    unsigned short* Ahi = (unsigned short*)ws;                              // 4 MiB
    unsigned short* Alo = (unsigned short*)(ws + (size_t)4 * 1024 * 1024);  // 4 MiB
    float* s_norm = (float*)(ws + (size_t)8 * 1024 * 1024);                 // 8 MiB
    float* sim    = (float*)(ws + (size_t)16 * 1024 * 1024);                // 64 MiB
    int* pos_idx  = (int*)(ws + (size_t)80 * 1024 * 1024);
    int* neg_idx  = (int*)(ws + (size_t)80 * 1024 * 1024 + (size_t)N * KPOS * sizeof(int));

    norm_kernel<<<2048, 256, 0, stream>>>(anchor, sample, Ahi, Alo, s_norm);

    dim3 ggrid(N / 128, N / 128);
    gemm_bf16<<<ggrid, 256, 0, stream>>>(Ahi, Alo, sim);

    topk_kernel<<<N / 4, 256, 0, stream>>>(sim, pos_idx, neg_idx);

    hipMemsetAsync(d_out, 0, sizeof(float), stream);
    loss_kernel<<<LOSS_BLOCKS, 256, 0, stream>>>(s_norm, pos_idx, neg_idx, out);
}